// Round 14
// baseline (119.197 us; speedup 1.0000x reference)
//
#include <hip/hip_runtime.h>
#include <stdint.h>

typedef __bf16 bf16x8 __attribute__((ext_vector_type(8)));
typedef float f32x4 __attribute__((ext_vector_type(4)));

static constexpr int B_ = 2, S_ = 2048, D_ = 1024, H_ = 16, HD_ = 64;
static constexpr int M_ = B_ * S_;                         // 4096
static constexpr size_t HSZ = (size_t)B_ * H_ * S_ * HD_;  // 4,194,304 elems per Q/K/V

#define DEV_INLINE __device__ __forceinline__

// 1/sqrt(HD) * log2(e) -- folded into Q at projection time (softmax runs base-2)
#define SC2F (0.125f * 1.4426950408889634f)

// raw v_exp_f32 (1 instr). exp2f() w/o fast-math is a multi-instr libcall.
#define EXP2(x) __builtin_amdgcn_exp2f(x)

DEV_INLINE uint16_t f2bf(float f) {
  __bf16 h = (__bf16)f;  // RNE; compiler packs pairs into v_cvt_pk_bf16_f32
  return __builtin_bit_cast(uint16_t, h);
}
DEV_INLINE float bf2f(uint16_t u) {
  uint32_t x = (uint32_t)u << 16;
  return __builtin_bit_cast(float, x);
}
DEV_INLINE float fmax3(float a, float b, float c) { return fmaxf(fmaxf(a, b), c); }

#define GLD16(gptr, lptr)                                                        \
  __builtin_amdgcn_global_load_lds(                                              \
      (const __attribute__((address_space(1))) void*)(gptr),                     \
      (__attribute__((address_space(3))) void*)(lptr), 16, 0, 0)

// ---------------- x -> bf16 ----------------
__global__ void cvt_x_kernel(const float* __restrict__ x, uint16_t* __restrict__ xb) {
  int i = blockIdx.x * 256 + threadIdx.x;
  float4 v = reinterpret_cast<const float4*>(x)[i];
  ushort4 o;
  o.x = f2bf(v.x); o.y = f2bf(v.y); o.z = f2bf(v.z); o.w = f2bf(v.w);
  reinterpret_cast<ushort4*>(xb)[i] = o;
}

// ---------------- W (4x) -> W^T bf16, concatenated [4*1024][1024] ----------------
__global__ void tr_w_kernel(const float* __restrict__ W0, const float* __restrict__ W1,
                            const float* __restrict__ W2, const float* __restrict__ W3,
                            uint16_t* __restrict__ Wt) {
  __shared__ float tile[32][33];
  const float* W = (blockIdx.z == 0) ? W0 : (blockIdx.z == 1) ? W1
                   : (blockIdx.z == 2) ? W2 : W3;
  uint16_t* dst = Wt + (size_t)blockIdx.z * D_ * D_;
  int c = blockIdx.x * 32 + threadIdx.x;   // source col n
  int r0 = blockIdx.y * 32;                // source row k
#pragma unroll
  for (int j = threadIdx.y; j < 32; j += 8)
    tile[j][threadIdx.x] = W[(size_t)(r0 + j) * D_ + c];
  __syncthreads();
  int oc = blockIdx.y * 32 + threadIdx.x;  // dest col  = k
  int or0 = blockIdx.x * 32;               // dest row  = n
#pragma unroll
  for (int j = threadIdx.y; j < 32; j += 8)
    dst[(size_t)(or0 + j) * D_ + oc] = f2bf(tile[threadIdx.x][j]);
}

// ---------------- GEMM: C[M][N] = A[M][K] * Bt[N][K]^T ----------------
template <int EPI, int BM, int MINW>
__global__ __launch_bounds__(256, MINW)
void gemm_bt_kernel(const uint16_t* __restrict__ A, const uint16_t* __restrict__ Bt,
                    uint16_t* __restrict__ Cb, float* __restrict__ Cf,
                    const float* __restrict__ bias, int K, int gx, int chunk) {
  constexpr int MR = BM / 32;                 // m-frags per wave
  __shared__ uint16_t ldsA[2][BM * 32];
  __shared__ uint16_t ldsB[2][128 * 32];
  const int tid = threadIdx.x;
  const int lane = tid & 63;
  const int wid = tid >> 6;
  const int lo = lane & 15, hi = lane >> 4;

  const int id = blockIdx.x;
  const int tilei = (id & 7) * chunk + (id >> 3);
  const int bx = tilei % gx, by = tilei / gx;
  const int row0 = by * BM, col0 = bx * 128;
  const int wr = (wid >> 1) * (BM / 2), wc = (wid & 1) * 64;

  const uint16_t* gA = A + (size_t)(row0 + (tid >> 2)) * K + (tid & 3) * 8;
  const uint16_t* gB = Bt + (size_t)(col0 + (tid >> 2)) * K + (tid & 3) * 8;

  f32x4 acc[MR][4] = {};

  auto stage = [&](int kt, int buf) {
    const uint16_t* a = gA + kt * 32;
    const uint16_t* b = gB + kt * 32;
    char* la = (char*)&ldsA[buf][0] + tid * 16;
    char* lb = (char*)&ldsB[buf][0] + tid * 16;
    GLD16(a, la);
    if constexpr (BM == 128) GLD16(a + (size_t)64 * K, la + 4096);
    GLD16(b, lb);
    GLD16(b + (size_t)64 * K, lb + 4096);
  };

  const int nk = K >> 5;
  stage(0, 0);
  __syncthreads();
  for (int kt = 0; kt < nk; ++kt) {
    const int cur = kt & 1;
    if (kt + 1 < nk) stage(kt + 1, cur ^ 1);
    const uint16_t* lA = &ldsA[cur][0];
    const uint16_t* lB = &ldsB[cur][0];
    bf16x8 af[MR], bfr[4];
#pragma unroll
    for (int m = 0; m < MR; ++m)
      af[m] = *(const bf16x8*)(lA + (wr + m * 16 + lo) * 32 + hi * 8);
#pragma unroll
    for (int n = 0; n < 4; ++n)
      bfr[n] = *(const bf16x8*)(lB + (wc + n * 16 + lo) * 32 + hi * 8);
    __builtin_amdgcn_s_setprio(1);
#pragma unroll
    for (int m = 0; m < MR; ++m)
#pragma unroll
      for (int n = 0; n < 4; ++n)
        acc[m][n] = __builtin_amdgcn_mfma_f32_16x16x32_bf16(af[m], bfr[n], acc[m][n], 0, 0, 0);
    __builtin_amdgcn_s_setprio(0);
    __syncthreads();
  }

#pragma unroll
  for (int m = 0; m < MR; ++m)
#pragma unroll
    for (int n = 0; n < 4; ++n) {
      const int gr0 = row0 + wr + m * 16 + hi * 4;  // 4 consecutive rows (j)
      const int gc = col0 + wc + n * 16 + lo;
      if (EPI == 0) {
        const int which = gc >> 10, c = gc & 1023;
        const int hh = c >> 6, d = c & 63;
        const int bb = gr0 >> 11, s0 = gr0 & 2047;
        if (which == 2) {
          // V^T: [b][h][d][s] -- 4 consecutive s pack into one 8B write
          ushort4 pk;
          pk.x = f2bf(acc[m][n][0]); pk.y = f2bf(acc[m][n][1]);
          pk.z = f2bf(acc[m][n][2]); pk.w = f2bf(acc[m][n][3]);
          *reinterpret_cast<ushort4*>(
              &Cb[2 * HSZ + ((size_t)(bb * H_ + hh) * HD_ + d) * S_ + s0]) = pk;
        } else {
          const float qs = (which == 0) ? SC2F : 1.0f;
#pragma unroll
          for (int j = 0; j < 4; ++j)
            Cb[(size_t)which * HSZ + (((size_t)(bb * H_ + hh) * S_ + s0 + j) * HD_ + d)] =
                f2bf(acc[m][n][j] * qs);
        }
      } else {
#pragma unroll
        for (int j = 0; j < 4; ++j)
          Cf[(size_t)(gr0 + j) * D_ + gc] = acc[m][n][j] + bias[gc];
      }
    }
}

// ---------------- causal flash attention (QBLK=256: fat waves) ----------------
// Key fact from R11/R13: per-wave K/V LDS reads are FIXED per kv-tile (each
// wave reads the full tile), so q-rows/wave sets the amortization. QBLK=256
// (4 waves x 64 q rows, mm=0..3) cuts total block-iters 272->144 per bh
// (-47% LDS traffic) at the same MFMA count. Every q-tile p (iters 4(p+1))
// is kv-split into 2 equal chunks -> 16 jobs/bh = 512 blocks; pairing
// (p7+p0, p6+p1, p5+p2, p4+p3) makes every CU-slot exactly 18 iters.
// XCD = g%8 = bh%8 (K/V L2-pinned). K/V in LDS (XOR-swizzled, dbuf), P via
// LDS, softmax per-lane (lane lo = q), row-sum via ones-MFMA, native exp2.
// Both chunks write unnormalized partials (c0 -> ctx, c1 -> Opart) + (m,l);
// merge normalizes. LDS 68KB -> 2 blocks/CU; launch_bounds(256,2).
__global__ __launch_bounds__(256, 2)
void attn_kernel(const uint16_t* __restrict__ QKV, uint16_t* __restrict__ ctx,
                 uint16_t* __restrict__ Opart, float2* __restrict__ ml) {
  __shared__ uint16_t ldsKV[2][2][4096];  // [buf][K/V][ks*2048 + row*32 + col8], swizzled
  __shared__ uint16_t ldsP[256][72];      // P[q][kv], pad 64->72

  // jt2[r][k] = p*2 + c.  Slot k gets (heavy round 0, light round 1) summing 18.
  static const uint8_t jt2[2][8] = {
      {14, 15, 12, 13, 10, 11, 8, 9},   // p7c0,p7c1,p6c0,p6c1,p5c0,p5c1,p4c0,p4c1
      {0, 1, 2, 3, 4, 5, 6, 7},         // p0c0,p0c1,p1c0,p1c1,p2c0,p2c1,p3c0,p3c1
  };

  const int tid = threadIdx.x;
  const int lane = tid & 63;
  const int w = tid >> 6;
  const int lo = lane & 15, hi = lane >> 4;
  const int swz = (hi * 8) ^ ((lo & 6) << 2);  // swizzled col for K/V reads

  const int g = blockIdx.x;
  const int bh = g & 31, k = (g >> 5) & 7, r = g >> 8;
  const int j = jt2[r][k];
  const int p = j >> 1, c = j & 1;
  const int half = 2 * (p + 1);
  const int k0 = c ? half : 0;
  const int k1 = c ? 2 * half : half;
  const int h = bh & 15, b = bh >> 4;

  const size_t bhs = ((size_t)(b * H_ + h)) * S_ * HD_;
  const uint16_t* Q  = QKV + bhs;                // [s][d], pre-scaled by SC2F
  const uint16_t* Kp = QKV + HSZ + bhs;          // [s][d]
  const uint16_t* Vt = QKV + 2 * HSZ + bhs;      // [d][s]

  // ones A-fragment for the l = sum(P) MFMA
  bf16x8 ones;
#pragma unroll
  for (int e = 0; e < 8; ++e) ones[e] = __builtin_bit_cast(__bf16, (uint16_t)0x3F80);

  // staging with inverse-swizzled global source (rule: swizzle both sides)
  const int srow = tid >> 2;                                  // 0..63
  const int scol = ((tid & 3) ^ ((tid >> 3) & 3)) * 8;        // swizzled col
  auto stage = [&](int kt, int bufi) {
    const uint16_t* gk = Kp + (size_t)(kt * 64 + srow) * HD_ + scol;
    char* lk = (char*)&ldsKV[bufi][0][0] + tid * 16;
    GLD16(gk, lk);             // d 0..31 half
    GLD16(gk + 32, lk + 4096); // d 32..63 half
    const uint16_t* gv = Vt + (size_t)srow * S_ + kt * 64 + scol;
    char* lv = (char*)&ldsKV[bufi][1][0] + tid * 16;
    GLD16(gv, lv);             // kv 0..31 half
    GLD16(gv + 32, lv + 4096); // kv 32..63 half
  };

  const int q0w = p * 256 + w * 64;   // wave owns q rows [q0w, q0w+64)
  // Q fragments (B-operand of mfma(K,Q)): lane lo = q col, hi*8 = d
  bf16x8 qf[4][2];
#pragma unroll
  for (int mm = 0; mm < 4; ++mm)
#pragma unroll
    for (int ks = 0; ks < 2; ++ks)
      qf[mm][ks] = *(const bf16x8*)(Q + (size_t)(q0w + mm * 16 + lo) * HD_ + ks * 32 + hi * 8);

  f32x4 acco[4][4] = {};       // O^T: [mm][nd], lane lo = q, row = d
  f32x4 lacc[4] = {};          // l accumulator (all 4 rows equal)
  float mstate[4] = {-1e30f, -1e30f, -1e30f, -1e30f};

  stage(k0, k0 & 1);
  asm volatile("s_waitcnt vmcnt(0)" ::: "memory");
  __builtin_amdgcn_s_barrier();
  __builtin_amdgcn_sched_barrier(0);

  for (int kt = k0; kt < k1; ++kt) {
    const int buf = kt & 1;
    if (kt + 1 < k1) stage(kt + 1, buf ^ 1);

    const bool active = (kt * 64) < (q0w + 64);  // wave not fully above diagonal
    if (active) {
      const uint16_t* lK = &ldsKV[buf][0][0];
      bf16x8 ak[4][2];
#pragma unroll
      for (int n = 0; n < 4; ++n)
#pragma unroll
        for (int ks = 0; ks < 2; ++ks)
          ak[n][ks] = *(const bf16x8*)(lK + ks * 2048 + (n * 16 + lo) * 32 + swz);

      const bool needMask = (kt * 64 + 63 > q0w);

      // ---- per-mm: QK^T, mask, softmax, P-write (keeps st liveness small) ----
#pragma unroll
      for (int mm = 0; mm < 4; ++mm) {
        f32x4 st[4];
        __builtin_amdgcn_s_setprio(1);
#pragma unroll
        for (int n = 0; n < 4; ++n) {
          f32x4 z = {};
          z = __builtin_amdgcn_mfma_f32_16x16x32_bf16(ak[n][0], qf[mm][0], z, 0, 0, 0);
          st[n] = __builtin_amdgcn_mfma_f32_16x16x32_bf16(ak[n][1], qf[mm][1], z, 0, 0, 0);
        }
        __builtin_amdgcn_s_setprio(0);

        if (needMask) {
          const int qg = q0w + mm * 16 + lo;
#pragma unroll
          for (int n = 0; n < 4; ++n)
#pragma unroll
            for (int jj = 0; jj < 4; ++jj) {
              int kvg = kt * 64 + n * 16 + hi * 4 + jj;
              if (kvg > qg) st[n][jj] = -1e30f;
            }
        }

        float t0 = fmax3(st[0][0], st[0][1], st[0][2]);
        float t1 = fmax3(t0, st[0][3], st[1][0]);
        float t2 = fmax3(t1, st[1][1], st[1][2]);
        float t3 = fmax3(t2, st[1][3], st[2][0]);
        float t4 = fmax3(t3, st[2][1], st[2][2]);
        float t5 = fmax3(t4, st[2][3], st[3][0]);
        float t6 = fmax3(t5, st[3][1], st[3][2]);
        float vmax = fmaxf(t6, st[3][3]);
        vmax = fmaxf(vmax, __shfl_xor(vmax, 16));
        vmax = fmaxf(vmax, __shfl_xor(vmax, 32));

        if (__any(vmax > mstate[mm] + 8.f)) {  // defer-max rescale
          float mnew = fmaxf(mstate[mm], vmax);
          float sc = EXP2(mstate[mm] - mnew);
          mstate[mm] = mnew;
          lacc[mm] *= sc;
#pragma unroll
          for (int nd = 0; nd < 4; ++nd)
#pragma unroll
            for (int jj = 0; jj < 4; ++jj) acco[mm][nd][jj] *= sc;
        }

#pragma unroll
        for (int n = 0; n < 4; ++n) {
          ushort4 pk;
          pk.x = f2bf(EXP2(st[n][0] - mstate[mm]));
          pk.y = f2bf(EXP2(st[n][1] - mstate[mm]));
          pk.z = f2bf(EXP2(st[n][2] - mstate[mm]));
          pk.w = f2bf(EXP2(st[n][3] - mstate[mm]));
          *reinterpret_cast<ushort4*>(&ldsP[w * 64 + mm * 16 + lo][n * 16 + hi * 4]) = pk;
        }
      }

      // ---- O^T += V^T P^T ; l += ones * P^T ----
      const uint16_t* lV = &ldsKV[buf][1][0];
      bf16x8 bv[4][2];
#pragma unroll
      for (int nd = 0; nd < 4; ++nd)
#pragma unroll
        for (int ks = 0; ks < 2; ++ks)
          bv[nd][ks] = *(const bf16x8*)(lV + ks * 2048 + (nd * 16 + lo) * 32 + swz);
#pragma unroll
      for (int mm = 0; mm < 4; ++mm) {
        bf16x8 ap0 = *(const bf16x8*)(&ldsP[w * 64 + mm * 16 + lo][hi * 8]);
        bf16x8 ap1 = *(const bf16x8*)(&ldsP[w * 64 + mm * 16 + lo][32 + hi * 8]);
        __builtin_amdgcn_s_setprio(1);
        lacc[mm] = __builtin_amdgcn_mfma_f32_16x16x32_bf16(ones, ap0, lacc[mm], 0, 0, 0);
        lacc[mm] = __builtin_amdgcn_mfma_f32_16x16x32_bf16(ones, ap1, lacc[mm], 0, 0, 0);
#pragma unroll
        for (int nd = 0; nd < 4; ++nd) {
          acco[mm][nd] = __builtin_amdgcn_mfma_f32_16x16x32_bf16(bv[nd][0], ap0, acco[mm][nd], 0, 0, 0);
          acco[mm][nd] = __builtin_amdgcn_mfma_f32_16x16x32_bf16(bv[nd][1], ap1, acco[mm][nd], 0, 0, 0);
        }
        __builtin_amdgcn_s_setprio(0);
      }
    }

    asm volatile("s_waitcnt vmcnt(0)" ::: "memory");
    __builtin_amdgcn_s_barrier();
    __builtin_amdgcn_sched_barrier(0);
  }

  // ---- write unnormalized partial + (m,l): c0 -> ctx, c1 -> Opart ----
  const int idx = bh * 8 + p;
#pragma unroll
  for (int mm = 0; mm < 4; ++mm) {
    const int qloc = w * 64 + mm * 16 + lo;
    uint16_t* dst;
    if (c == 0)
      dst = ctx + (size_t)(b * S_ + p * 256 + qloc) * D_ + h * HD_;
    else
      dst = Opart + (size_t)idx * 16384 + (size_t)qloc * 64;
#pragma unroll
    for (int nd = 0; nd < 4; ++nd) {
      ushort4 pk;
      pk.x = f2bf(acco[mm][nd][0]); pk.y = f2bf(acco[mm][nd][1]);
      pk.z = f2bf(acco[mm][nd][2]); pk.w = f2bf(acco[mm][nd][3]);
      *reinterpret_cast<ushort4*>(dst + nd * 16 + hi * 4) = pk;
    }
    if (hi == 0) ml[(idx * 2 + c) * 256 + qloc] = make_float2(mstate[mm], lacc[mm][0]);
  }
}

// ---------------- merge kv-split halves -> normalized ctx ---------------------
// 1024 blocks x 256 threads; thread -> (row = (bh,p,q), 16-d chunk).
// c0 partial lives in ctx (in place), c1 in Opart.
__global__ void merge_kernel(const uint16_t* __restrict__ Opart,
                             const float2* __restrict__ ml,
                             uint16_t* __restrict__ ctx) {
  const int t = blockIdx.x * 256 + threadIdx.x;   // 262144 threads
  const int dh = t & 3, row = t >> 2;
  const int q = row & 255, p = (row >> 8) & 7, bh = row >> 11;
  const int h = bh & 15, b = bh >> 4;
  const int idx = bh * 8 + p;

  const float2 A = ml[(idx * 2 + 0) * 256 + q];
  const float2 Bv = ml[(idx * 2 + 1) * 256 + q];
  const float m = fmaxf(A.x, Bv.x);
  float sa = EXP2(A.x - m), sb = EXP2(Bv.x - m);
  const float inv = 1.f / (A.y * sa + Bv.y * sb);
  sa *= inv; sb *= inv;

  uint16_t* pc = ctx + ((size_t)(b * S_) + p * 256 + q) * D_ + h * HD_ + dh * 16;
  const uint16_t* pb = Opart + (size_t)idx * 16384 + (size_t)q * 64 + dh * 16;
#pragma unroll
  for (int hf = 0; hf < 2; ++hf) {
    int4 va = ((const int4*)pc)[hf], vb = ((const int4*)pb)[hf];
    const uint16_t* ua = (const uint16_t*)&va;
    const uint16_t* ub = (const uint16_t*)&vb;
    int4 vo;
    uint16_t* uo = (uint16_t*)&vo;
#pragma unroll
    for (int i = 0; i < 8; ++i)
      uo[i] = f2bf(bf2f(ua[i]) * sa + bf2f(ub[i]) * sb);
    ((int4*)pc)[hf] = vo;
  }
}

extern "C" void kernel_launch(void* const* d_in, const int* in_sizes, int n_in,
                              void* d_out, int out_size, void* d_ws, size_t ws_size,
                              hipStream_t stream) {
  (void)in_sizes; (void)n_in; (void)out_size; (void)ws_size;
  const float* x  = (const float*)d_in[0];
  const float* Wq = (const float*)d_in[1];
  const float* Wk = (const float*)d_in[2];
  const float* Wv = (const float*)d_in[3];
  const float* Wo = (const float*)d_in[4];
  const float* bo = (const float*)d_in[5];
  float* out = (float*)d_out;

  uint16_t* ws  = (uint16_t*)d_ws;
  uint16_t* xb  = ws;                         // 4096*1024 (dead after gemm0)
  uint16_t* Wt  = xb + (size_t)M_ * D_;       // 4*1024*1024 (Wq^T dead after gemm0)
  uint16_t* QKV = Wt + (size_t)4 * D_ * D_;   // 3*HSZ (Q, K, V^T)
  uint16_t* ctx = QKV + 3 * HSZ;              // 4096*1024   (~48 MB total)
  // kv-split partials reuse dead regions (attn runs after gemm0):
  uint16_t* Opart = xb;                       // 32*8*16384 elems = 8.39 MB (== xb)
  float2*   mlbuf = (float2*)Wt;              // 32*8*2*256 float2 = 1 MB (dead Wq^T)

  cvt_x_kernel<<<(M_ * D_) / 1024, 256, 0, stream>>>(x, xb);
  tr_w_kernel<<<dim3(32, 32, 4), dim3(32, 8), 0, stream>>>(Wq, Wk, Wv, Wo, Wt);
  // gemm<0>: 24x32 tiles = 768 blocks, 3/CU uniform (chunk=96)
  gemm_bt_kernel<0, 128, 3><<<768, 256, 0, stream>>>(xb, Wt, QKV, nullptr, nullptr, D_, 24, 96);
  attn_kernel<<<512, 256, 0, stream>>>(QKV, ctx, Opart, mlbuf);
  merge_kernel<<<1024, 256, 0, stream>>>(Opart, mlbuf, ctx);
  // gemm<1>: BM=64 -> 64x8 tiles = 512 blocks, 2/CU (chunk=64)
  gemm_bt_kernel<1, 64, 2><<<512, 256, 0, stream>>>(ctx, Wt + (size_t)3 * D_ * D_, nullptr, out, bo, D_, 8, 64);
}

// Round 15
// 110.557 us; speedup vs baseline: 1.0781x; 1.0781x over previous
//
#include <hip/hip_runtime.h>
#include <stdint.h>

typedef __bf16 bf16x8 __attribute__((ext_vector_type(8)));
typedef float f32x4 __attribute__((ext_vector_type(4)));

static constexpr int B_ = 2, S_ = 2048, D_ = 1024, H_ = 16, HD_ = 64;
static constexpr int M_ = B_ * S_;                         // 4096
static constexpr size_t HSZ = (size_t)B_ * H_ * S_ * HD_;  // 4,194,304 elems per Q/K/V

#define DEV_INLINE __device__ __forceinline__

// 1/sqrt(HD) * log2(e) -- folded into Q at projection time (softmax runs base-2)
#define SC2F (0.125f * 1.4426950408889634f)

// raw v_exp_f32 (1 instr). exp2f() w/o fast-math is a multi-instr libcall.
#define EXP2(x) __builtin_amdgcn_exp2f(x)

DEV_INLINE uint16_t f2bf(float f) {
  __bf16 h = (__bf16)f;  // RNE; compiler packs pairs into v_cvt_pk_bf16_f32
  return __builtin_bit_cast(uint16_t, h);
}
DEV_INLINE float bf2f(uint16_t u) {
  uint32_t x = (uint32_t)u << 16;
  return __builtin_bit_cast(float, x);
}
DEV_INLINE float fmax3(float a, float b, float c) { return fmaxf(fmaxf(a, b), c); }

#define GLD16(gptr, lptr)                                                        \
  __builtin_amdgcn_global_load_lds(                                              \
      (const __attribute__((address_space(1))) void*)(gptr),                     \
      (__attribute__((address_space(3))) void*)(lptr), 16, 0, 0)

// ---------------- x -> bf16 ----------------
__global__ void cvt_x_kernel(const float* __restrict__ x, uint16_t* __restrict__ xb) {
  int i = blockIdx.x * 256 + threadIdx.x;
  float4 v = reinterpret_cast<const float4*>(x)[i];
  ushort4 o;
  o.x = f2bf(v.x); o.y = f2bf(v.y); o.z = f2bf(v.z); o.w = f2bf(v.w);
  reinterpret_cast<ushort4*>(xb)[i] = o;
}

// ---------------- W (4x) -> W^T bf16, concatenated [4*1024][1024] ----------------
__global__ void tr_w_kernel(const float* __restrict__ W0, const float* __restrict__ W1,
                            const float* __restrict__ W2, const float* __restrict__ W3,
                            uint16_t* __restrict__ Wt) {
  __shared__ float tile[32][33];
  const float* W = (blockIdx.z == 0) ? W0 : (blockIdx.z == 1) ? W1
                   : (blockIdx.z == 2) ? W2 : W3;
  uint16_t* dst = Wt + (size_t)blockIdx.z * D_ * D_;
  int c = blockIdx.x * 32 + threadIdx.x;   // source col n
  int r0 = blockIdx.y * 32;                // source row k
#pragma unroll
  for (int j = threadIdx.y; j < 32; j += 8)
    tile[j][threadIdx.x] = W[(size_t)(r0 + j) * D_ + c];
  __syncthreads();
  int oc = blockIdx.y * 32 + threadIdx.x;  // dest col  = k
  int or0 = blockIdx.x * 32;               // dest row  = n
#pragma unroll
  for (int j = threadIdx.y; j < 32; j += 8)
    dst[(size_t)(or0 + j) * D_ + oc] = f2bf(tile[threadIdx.x][j]);
}

// ---------------- GEMM: C[M][N] = A[M][K] * Bt[N][K]^T ----------------
// Triple-buffered global_load_lds staging with COUNTED vmcnt (T4): tile kt+2's
// loads stay in flight across the barrier; the barrier only waits for kt+1
// (prefetched a full iteration earlier). L = loads/stage = 4 (BM=128) / 3 (BM=64).
template <int EPI, int BM, int MINW>
__global__ __launch_bounds__(256, MINW)
void gemm_bt_kernel(const uint16_t* __restrict__ A, const uint16_t* __restrict__ Bt,
                    uint16_t* __restrict__ Cb, float* __restrict__ Cf,
                    const float* __restrict__ bias, int K, int gx, int chunk) {
  constexpr int MR = BM / 32;                 // m-frags per wave
  __shared__ uint16_t ldsA[3][BM * 32];
  __shared__ uint16_t ldsB[3][128 * 32];
  const int tid = threadIdx.x;
  const int lane = tid & 63;
  const int wid = tid >> 6;
  const int lo = lane & 15, hi = lane >> 4;

  const int id = blockIdx.x;
  const int tilei = (id & 7) * chunk + (id >> 3);
  const int bx = tilei % gx, by = tilei / gx;
  const int row0 = by * BM, col0 = bx * 128;
  const int wr = (wid >> 1) * (BM / 2), wc = (wid & 1) * 64;

  const uint16_t* gA = A + (size_t)(row0 + (tid >> 2)) * K + (tid & 3) * 8;
  const uint16_t* gB = Bt + (size_t)(col0 + (tid >> 2)) * K + (tid & 3) * 8;

  f32x4 acc[MR][4] = {};

  auto stage = [&](int kt, int buf) {
    const uint16_t* a = gA + kt * 32;
    const uint16_t* b = gB + kt * 32;
    char* la = (char*)&ldsA[buf][0] + tid * 16;
    char* lb = (char*)&ldsB[buf][0] + tid * 16;
    GLD16(a, la);
    if constexpr (BM == 128) GLD16(a + (size_t)64 * K, la + 4096);
    GLD16(b, lb);
    GLD16(b + (size_t)64 * K, lb + 4096);
  };

  const int nk = K >> 5;
  stage(0, 0);
  stage(1, 1);
  if constexpr (BM == 128) asm volatile("s_waitcnt vmcnt(4)" ::: "memory");
  else                     asm volatile("s_waitcnt vmcnt(3)" ::: "memory");
  __builtin_amdgcn_s_barrier();
  __builtin_amdgcn_sched_barrier(0);

  for (int kt = 0; kt < nk; ++kt) {
    const int cur = kt % 3;
    const bool staged = (kt + 2 < nk);
    if (staged) stage(kt + 2, (kt + 2) % 3);

    const uint16_t* lA = &ldsA[cur][0];
    const uint16_t* lB = &ldsB[cur][0];
    bf16x8 af[MR], bfr[4];
#pragma unroll
    for (int m = 0; m < MR; ++m)
      af[m] = *(const bf16x8*)(lA + (wr + m * 16 + lo) * 32 + hi * 8);
#pragma unroll
    for (int n = 0; n < 4; ++n)
      bfr[n] = *(const bf16x8*)(lB + (wc + n * 16 + lo) * 32 + hi * 8);
    __builtin_amdgcn_s_setprio(1);
#pragma unroll
    for (int m = 0; m < MR; ++m)
#pragma unroll
      for (int n = 0; n < 4; ++n)
        acc[m][n] = __builtin_amdgcn_mfma_f32_16x16x32_bf16(af[m], bfr[n], acc[m][n], 0, 0, 0);
    __builtin_amdgcn_s_setprio(0);

    if (staged) {
      if constexpr (BM == 128) asm volatile("s_waitcnt vmcnt(4)" ::: "memory");
      else                     asm volatile("s_waitcnt vmcnt(3)" ::: "memory");
    } else {
      asm volatile("s_waitcnt vmcnt(0)" ::: "memory");
    }
    __builtin_amdgcn_s_barrier();
    __builtin_amdgcn_sched_barrier(0);
  }

#pragma unroll
  for (int m = 0; m < MR; ++m)
#pragma unroll
    for (int n = 0; n < 4; ++n) {
      const int gr0 = row0 + wr + m * 16 + hi * 4;  // 4 consecutive rows (j)
      const int gc = col0 + wc + n * 16 + lo;
      if (EPI == 0) {
        const int which = gc >> 10, c = gc & 1023;
        const int hh = c >> 6, d = c & 63;
        const int bb = gr0 >> 11, s0 = gr0 & 2047;
        if (which == 2) {
          // V^T: [b][h][d][s] -- 4 consecutive s pack into one 8B write
          ushort4 pk;
          pk.x = f2bf(acc[m][n][0]); pk.y = f2bf(acc[m][n][1]);
          pk.z = f2bf(acc[m][n][2]); pk.w = f2bf(acc[m][n][3]);
          *reinterpret_cast<ushort4*>(
              &Cb[2 * HSZ + ((size_t)(bb * H_ + hh) * HD_ + d) * S_ + s0]) = pk;
        } else {
          const float qs = (which == 0) ? SC2F : 1.0f;
#pragma unroll
          for (int j = 0; j < 4; ++j)
            Cb[(size_t)which * HSZ + (((size_t)(bb * H_ + hh) * S_ + s0 + j) * HD_ + d)] =
                f2bf(acc[m][n][j] * qs);
        }
      } else {
#pragma unroll
        for (int j = 0; j < 4; ++j)
          Cf[(size_t)(gr0 + j) * D_ + gc] = acc[m][n][j] + bias[gc];
      }
    }
}

// ---------------- causal flash attention (QBLK=128, exact-packed grid) --------
// Session-best structure (R11: attn <40us, total 108us) -- reverted verbatim.
// 768 blocks = 3 rounds x 256 CU-slots; slot = k*32 + bh -> XCD = bh%8.
// Triplet table: each CU-slot's 3 co-resident jobs sum to EXACTLY 34 iters.
// 4 waves x 32 q rows. Swapped QK^T + transposed PV; softmax per-lane (lo=q).
// K/V XOR-swizzled, double-buffered (50KB LDS -> 3 blocks/CU). Row-sum via
// ones-MFMA. Split jobs (p8..15 kv-halves) write partial (O,m,l).
__global__ __launch_bounds__(256, 3)
void attn_kernel(const uint16_t* __restrict__ QKV, uint16_t* __restrict__ ctx,
                 uint16_t* __restrict__ Opart, float2* __restrict__ ml) {
  __shared__ uint16_t ldsKV[2][2][4096];  // [buf][K/V][ks*2048 + row*32 + col8], swizzled
  __shared__ uint16_t ldsP[128][72];      // P[q][kv], pad 64->72

  // job table: (p<<2)|2|c for split-half c, (p<<2) for unsplit
  static const uint8_t jt[3][8] = {
      {0 << 2, 1 << 2, 2 << 2, 3 << 2, 4 << 2, 5 << 2, 6 << 2, (9 << 2) | 3},
      {(15 << 2) | 2, 7 << 2, (14 << 2) | 2, (14 << 2) | 3,
       (13 << 2) | 3, (12 << 2) | 3, (10 << 2) | 3, (11 << 2) | 2},
      {(15 << 2) | 3, (13 << 2) | 2, (12 << 2) | 2, (10 << 2) | 2,
       (9 << 2) | 2, (8 << 2) | 2, (8 << 2) | 3, (11 << 2) | 3},
  };

  const int tid = threadIdx.x;
  const int lane = tid & 63;
  const int w = tid >> 6;
  const int lo = lane & 15, hi = lane >> 4;
  const int swz = (hi * 8) ^ ((lo & 6) << 2);  // swizzled col for K/V reads

  const int g = blockIdx.x;
  const int bh = g & 31, k = (g >> 5) & 7, r = g >> 8;
  const int j = jt[r][k];
  const int p = j >> 2;
  const bool split = (j & 2) != 0;
  const int c = j & 1;
  const int k0 = (split && c) ? (p + 1) : 0;
  const int k1 = (split && !c) ? (p + 1) : (2 * p + 2);
  const int h = bh & 15, b = bh >> 4;

  const size_t bhs = ((size_t)(b * H_ + h)) * S_ * HD_;
  const uint16_t* Q  = QKV + bhs;                // [s][d], pre-scaled by SC2F
  const uint16_t* Kp = QKV + HSZ + bhs;          // [s][d]
  const uint16_t* Vt = QKV + 2 * HSZ + bhs;      // [d][s]

  // ones A-fragment for the l = sum(P) MFMA
  bf16x8 ones;
#pragma unroll
  for (int e = 0; e < 8; ++e) ones[e] = __builtin_bit_cast(__bf16, (uint16_t)0x3F80);

  // staging with inverse-swizzled global source (rule: swizzle both sides)
  const int srow = tid >> 2;                                  // 0..63
  const int scol = ((tid & 3) ^ ((tid >> 3) & 3)) * 8;        // swizzled col
  auto stage = [&](int kt, int bufi) {
    const uint16_t* gk = Kp + (size_t)(kt * 64 + srow) * HD_ + scol;
    char* lk = (char*)&ldsKV[bufi][0][0] + tid * 16;
    GLD16(gk, lk);             // d 0..31 half
    GLD16(gk + 32, lk + 4096); // d 32..63 half
    const uint16_t* gv = Vt + (size_t)srow * S_ + kt * 64 + scol;
    char* lv = (char*)&ldsKV[bufi][1][0] + tid * 16;
    GLD16(gv, lv);             // kv 0..31 half
    GLD16(gv + 32, lv + 4096); // kv 32..63 half
  };

  const int q0w = p * 128 + w * 32;
  // Q fragments (B-operand of mfma(K,Q)): lane lo = q col, hi*8 = d
  bf16x8 qf[2][2];
#pragma unroll
  for (int mm = 0; mm < 2; ++mm)
#pragma unroll
    for (int ks = 0; ks < 2; ++ks)
      qf[mm][ks] = *(const bf16x8*)(Q + (size_t)(q0w + mm * 16 + lo) * HD_ + ks * 32 + hi * 8);

  f32x4 acco[2][4] = {};       // O^T: lane lo = q, row = d (nd*16+hi*4+j)
  f32x4 lacc[2] = {};          // l accumulator (all 4 rows equal)
  float mstate[2] = {-1e30f, -1e30f};

  stage(k0, k0 & 1);
  asm volatile("s_waitcnt vmcnt(0)" ::: "memory");
  __builtin_amdgcn_s_barrier();
  __builtin_amdgcn_sched_barrier(0);

  for (int kt = k0; kt < k1; ++kt) {
    const int buf = kt & 1;
    if (kt + 1 < k1) stage(kt + 1, buf ^ 1);

    const bool active = (kt * 64) < (q0w + 32);  // wave not fully above diagonal
    if (active) {
      // ---- S^T = K Q^T : lane lo = q, rows kv = n*16+hi*4+j ----
      const uint16_t* lK = &ldsKV[buf][0][0];
      bf16x8 ak[4][2];
#pragma unroll
      for (int n = 0; n < 4; ++n)
#pragma unroll
        for (int ks = 0; ks < 2; ++ks)
          ak[n][ks] = *(const bf16x8*)(lK + ks * 2048 + (n * 16 + lo) * 32 + swz);

      f32x4 st[4][2];
      __builtin_amdgcn_s_setprio(1);
#pragma unroll
      for (int n = 0; n < 4; ++n)
#pragma unroll
        for (int mm = 0; mm < 2; ++mm) {
          f32x4 z = {};
          z = __builtin_amdgcn_mfma_f32_16x16x32_bf16(ak[n][0], qf[mm][0], z, 0, 0, 0);
          st[n][mm] = __builtin_amdgcn_mfma_f32_16x16x32_bf16(ak[n][1], qf[mm][1], z, 0, 0, 0);
        }
      __builtin_amdgcn_s_setprio(0);

      // ---- causal mask (tiles overlapping this wave's rows) ----
      if (kt * 64 + 63 > q0w) {
#pragma unroll
        for (int n = 0; n < 4; ++n)
#pragma unroll
          for (int mm = 0; mm < 2; ++mm) {
            const int qg = q0w + mm * 16 + lo;
#pragma unroll
            for (int jj = 0; jj < 4; ++jj) {
              int kvg = kt * 64 + n * 16 + hi * 4 + jj;
              if (kvg > qg) st[n][mm][jj] = -1e30f;
            }
          }
      }

      // ---- online softmax, per-lane state (q = lo) ----
#pragma unroll
      for (int mm = 0; mm < 2; ++mm) {
        float t0 = fmax3(st[0][mm][0], st[0][mm][1], st[0][mm][2]);
        float t1 = fmax3(t0, st[0][mm][3], st[1][mm][0]);
        float t2 = fmax3(t1, st[1][mm][1], st[1][mm][2]);
        float t3 = fmax3(t2, st[1][mm][3], st[2][mm][0]);
        float t4 = fmax3(t3, st[2][mm][1], st[2][mm][2]);
        float t5 = fmax3(t4, st[2][mm][3], st[3][mm][0]);
        float t6 = fmax3(t5, st[3][mm][1], st[3][mm][2]);
        float vmax = fmaxf(t6, st[3][mm][3]);
        vmax = fmaxf(vmax, __shfl_xor(vmax, 16));
        vmax = fmaxf(vmax, __shfl_xor(vmax, 32));

        if (__any(vmax > mstate[mm] + 8.f)) {  // defer-max rescale
          float mnew = fmaxf(mstate[mm], vmax);
          float sc = EXP2(mstate[mm] - mnew);
          mstate[mm] = mnew;
          lacc[mm] *= sc;
#pragma unroll
          for (int nd = 0; nd < 4; ++nd)
#pragma unroll
            for (int jj = 0; jj < 4; ++jj) acco[mm][nd][jj] *= sc;
        }

#pragma unroll
        for (int n = 0; n < 4; ++n) {
          ushort4 pk;
          pk.x = f2bf(EXP2(st[n][mm][0] - mstate[mm]));
          pk.y = f2bf(EXP2(st[n][mm][1] - mstate[mm]));
          pk.z = f2bf(EXP2(st[n][mm][2] - mstate[mm]));
          pk.w = f2bf(EXP2(st[n][mm][3] - mstate[mm]));
          *reinterpret_cast<ushort4*>(&ldsP[w * 32 + mm * 16 + lo][n * 16 + hi * 4]) = pk;
        }
      }

      // ---- O^T += V^T P^T ; l += ones * P^T ----
      const uint16_t* lV = &ldsKV[buf][1][0];
      bf16x8 ap[2][2], bv[4][2];
#pragma unroll
      for (int mm = 0; mm < 2; ++mm)
#pragma unroll
        for (int ks = 0; ks < 2; ++ks)
          ap[mm][ks] = *(const bf16x8*)(&ldsP[w * 32 + mm * 16 + lo][ks * 32 + hi * 8]);
#pragma unroll
      for (int nd = 0; nd < 4; ++nd)
#pragma unroll
        for (int ks = 0; ks < 2; ++ks)
          bv[nd][ks] = *(const bf16x8*)(lV + ks * 2048 + (nd * 16 + lo) * 32 + swz);
      __builtin_amdgcn_s_setprio(1);
#pragma unroll
      for (int mm = 0; mm < 2; ++mm) {
        lacc[mm] = __builtin_amdgcn_mfma_f32_16x16x32_bf16(ones, ap[mm][0], lacc[mm], 0, 0, 0);
        lacc[mm] = __builtin_amdgcn_mfma_f32_16x16x32_bf16(ones, ap[mm][1], lacc[mm], 0, 0, 0);
#pragma unroll
        for (int nd = 0; nd < 4; ++nd) {
          acco[mm][nd] = __builtin_amdgcn_mfma_f32_16x16x32_bf16(bv[nd][0], ap[mm][0], acco[mm][nd], 0, 0, 0);
          acco[mm][nd] = __builtin_amdgcn_mfma_f32_16x16x32_bf16(bv[nd][1], ap[mm][1], acco[mm][nd], 0, 0, 0);
        }
      }
      __builtin_amdgcn_s_setprio(0);
    }

    asm volatile("s_waitcnt vmcnt(0)" ::: "memory");
    __builtin_amdgcn_s_barrier();
    __builtin_amdgcn_sched_barrier(0);
  }

  if (!split) {
    // ---- normalize (per-lane) + packed ctx write ----
#pragma unroll
    for (int mm = 0; mm < 2; ++mm) {
      const float inv = 1.f / lacc[mm][0];
      uint16_t* crow = ctx + (size_t)(b * S_ + q0w + mm * 16 + lo) * D_ + h * HD_;
#pragma unroll
      for (int nd = 0; nd < 4; ++nd) {
        ushort4 pk;
        pk.x = f2bf(acco[mm][nd][0] * inv); pk.y = f2bf(acco[mm][nd][1] * inv);
        pk.z = f2bf(acco[mm][nd][2] * inv); pk.w = f2bf(acco[mm][nd][3] * inv);
        *reinterpret_cast<ushort4*>(crow + nd * 16 + hi * 4) = pk;
      }
    }
  } else {
    // ---- write partial O (unnormalized bf16) + (m,l): idx over (bh,p,c) ----
    const int idx = ((bh * 8) + (p - 8)) * 2 + c;
    uint16_t* op = Opart + (size_t)idx * 8192;   // 128 q x 64 d
#pragma unroll
    for (int mm = 0; mm < 2; ++mm) {
      const int qloc = w * 32 + mm * 16 + lo;
#pragma unroll
      for (int nd = 0; nd < 4; ++nd) {
        ushort4 pk;
        pk.x = f2bf(acco[mm][nd][0]); pk.y = f2bf(acco[mm][nd][1]);
        pk.z = f2bf(acco[mm][nd][2]); pk.w = f2bf(acco[mm][nd][3]);
        *reinterpret_cast<ushort4*>(op + qloc * 64 + nd * 16 + hi * 4) = pk;
      }
      if (hi == 0) ml[idx * 128 + qloc] = make_float2(mstate[mm], lacc[mm][0]);
    }
  }
}

// ---------------- merge kv-split partials -> ctx ------------------------------
// 512 blocks x 256 threads; thread -> (row = (bh,si,q), 16-d chunk).
__global__ void merge_kernel(const uint16_t* __restrict__ Opart,
                             const float2* __restrict__ ml,
                             uint16_t* __restrict__ ctx) {
  const int t = blockIdx.x * 256 + threadIdx.x;   // 131072 threads
  const int dh = t & 3, row = t >> 2;
  const int q = row & 127, si = (row >> 7) & 7, bh = row >> 10;
  const int h = bh & 15, b = bh >> 4;
  const int p = 8 + si;
  const int base = (bh * 8 + si) * 2;

  const float2 A = ml[base * 128 + q];
  const float2 Bv = ml[base * 128 + 128 + q];
  const float m = fmaxf(A.x, Bv.x);
  float sa = EXP2(A.x - m), sb = EXP2(Bv.x - m);
  const float inv = 1.f / (A.y * sa + Bv.y * sb);
  sa *= inv; sb *= inv;

  const uint16_t* Oa = Opart + (size_t)base * 8192 + q * 64 + dh * 16;
  const uint16_t* Ob = Oa + 8192;
  uint16_t* pc = ctx + ((size_t)(b * S_) + p * 128 + q) * D_ + h * HD_ + dh * 16;
#pragma unroll
  for (int hf = 0; hf < 2; ++hf) {
    int4 va = ((const int4*)Oa)[hf], vb = ((const int4*)Ob)[hf];
    const uint16_t* ua = (const uint16_t*)&va;
    const uint16_t* ub = (const uint16_t*)&vb;
    int4 vo;
    uint16_t* uo = (uint16_t*)&vo;
#pragma unroll
    for (int i = 0; i < 8; ++i)
      uo[i] = f2bf(bf2f(ua[i]) * sa + bf2f(ub[i]) * sb);
    ((int4*)pc)[hf] = vo;
  }
}

extern "C" void kernel_launch(void* const* d_in, const int* in_sizes, int n_in,
                              void* d_out, int out_size, void* d_ws, size_t ws_size,
                              hipStream_t stream) {
  (void)in_sizes; (void)n_in; (void)out_size; (void)ws_size;
  const float* x  = (const float*)d_in[0];
  const float* Wq = (const float*)d_in[1];
  const float* Wk = (const float*)d_in[2];
  const float* Wv = (const float*)d_in[3];
  const float* Wo = (const float*)d_in[4];
  const float* bo = (const float*)d_in[5];
  float* out = (float*)d_out;

  uint16_t* ws  = (uint16_t*)d_ws;
  uint16_t* xb  = ws;                         // 4096*1024 (dead after gemm0)
  uint16_t* Wt  = xb + (size_t)M_ * D_;       // 4*1024*1024 (Wq^T dead after gemm0)
  uint16_t* QKV = Wt + (size_t)4 * D_ * D_;   // 3*HSZ (Q, K, V^T)
  uint16_t* ctx = QKV + 3 * HSZ;              // 4096*1024   (~48 MB total)
  // kv-split partials reuse dead regions (attn runs after gemm0):
  uint16_t* Opart = xb;                       // 32*8*2*8192 elems = 8 MB (== xb)
  float2*   mlbuf = (float2*)Wt;              // 32*16*128 float2 = 512 KB (in dead Wq^T)

  cvt_x_kernel<<<(M_ * D_) / 1024, 256, 0, stream>>>(x, xb);
  tr_w_kernel<<<dim3(32, 32, 4), dim3(32, 8), 0, stream>>>(Wq, Wk, Wv, Wo, Wt);
  // gemm<0>: 24x32 tiles = 768 blocks, 3/CU uniform (chunk=96)
  gemm_bt_kernel<0, 128, 3><<<768, 256, 0, stream>>>(xb, Wt, QKV, nullptr, nullptr, D_, 24, 96);
  attn_kernel<<<768, 256, 0, stream>>>(QKV, ctx, Opart, mlbuf);
  merge_kernel<<<512, 256, 0, stream>>>(Opart, mlbuf, ctx);
  // gemm<1>: BM=64 -> 64x8 tiles = 512 blocks, 2/CU (chunk=64)
  gemm_bt_kernel<1, 64, 2><<<512, 256, 0, stream>>>(ctx, Wt + (size_t)3 * D_ * D_, nullptr, out, bo, D_, 8, 64);
}

// Round 16
// 105.289 us; speedup vs baseline: 1.1321x; 1.0500x over previous
//
#include <hip/hip_runtime.h>
#include <stdint.h>

typedef __bf16 bf16x8 __attribute__((ext_vector_type(8)));
typedef float f32x4 __attribute__((ext_vector_type(4)));

static constexpr int B_ = 2, S_ = 2048, D_ = 1024, H_ = 16, HD_ = 64;
static constexpr int M_ = B_ * S_;                         // 4096
static constexpr size_t HSZ = (size_t)B_ * H_ * S_ * HD_;  // 4,194,304 elems per Q/K/V

#define DEV_INLINE __device__ __forceinline__

// 1/sqrt(HD) * log2(e) -- folded into Q at projection time (softmax runs base-2)
#define SC2F (0.125f * 1.4426950408889634f)

// raw v_exp_f32 (1 instr). exp2f() w/o fast-math is a multi-instr libcall.
#define EXP2(x) __builtin_amdgcn_exp2f(x)

DEV_INLINE uint16_t f2bf(float f) {
  __bf16 h = (__bf16)f;  // RNE; compiler packs pairs into v_cvt_pk_bf16_f32
  return __builtin_bit_cast(uint16_t, h);
}
DEV_INLINE float bf2f(uint16_t u) {
  uint32_t x = (uint32_t)u << 16;
  return __builtin_bit_cast(float, x);
}
DEV_INLINE float fmax3(float a, float b, float c) { return fmaxf(fmaxf(a, b), c); }

#define GLD16(gptr, lptr)                                                        \
  __builtin_amdgcn_global_load_lds(                                              \
      (const __attribute__((address_space(1))) void*)(gptr),                     \
      (__attribute__((address_space(3))) void*)(lptr), 16, 0, 0)

// ---------------- fused prep: x -> bf16  AND  W (4x) -> W^T bf16 --------------
// blocks 0..4095: convert x (one float4/thread). blocks 4096..8191: transpose
// one 32x32 tile of one of the 4 weight matrices. Uniform 256-thread blocks;
// branch is block-uniform so the barrier in the transpose path is safe.
__global__ __launch_bounds__(256)
void prep_kernel(const float* __restrict__ x,
                 const float* __restrict__ W0, const float* __restrict__ W1,
                 const float* __restrict__ W2, const float* __restrict__ W3,
                 uint16_t* __restrict__ xb, uint16_t* __restrict__ Wt) {
  __shared__ float tile[32][33];
  const int id = blockIdx.x;
  const int tid = threadIdx.x;
  if (id < 4096) {
    int i = id * 256 + tid;
    float4 v = reinterpret_cast<const float4*>(x)[i];
    ushort4 o;
    o.x = f2bf(v.x); o.y = f2bf(v.y); o.z = f2bf(v.z); o.w = f2bf(v.w);
    reinterpret_cast<ushort4*>(xb)[i] = o;
  } else {
    const int v = id - 4096;
    const int bx = v & 31, by = (v >> 5) & 31, z = v >> 10;
    const float* W = (z == 0) ? W0 : (z == 1) ? W1 : (z == 2) ? W2 : W3;
    uint16_t* dst = Wt + (size_t)z * D_ * D_;
    const int tx = tid & 31, ty = tid >> 5;   // 32 x 8
    const int c = bx * 32 + tx;               // source col n
    const int r0 = by * 32;                   // source row k
#pragma unroll
    for (int j = ty; j < 32; j += 8)
      tile[j][tx] = W[(size_t)(r0 + j) * D_ + c];
    __syncthreads();
    const int oc = by * 32 + tx;              // dest col = k
    const int or0 = bx * 32;                  // dest row = n
#pragma unroll
    for (int j = ty; j < 32; j += 8)
      dst[(size_t)(or0 + j) * D_ + oc] = f2bf(tile[tx][j]);
  }
}

// ---------------- GEMM: C[M][N] = A[M][K] * Bt[N][K]^T ----------------
// R11's double-buffered structure (best measured).
template <int EPI, int BM, int MINW>
__global__ __launch_bounds__(256, MINW)
void gemm_bt_kernel(const uint16_t* __restrict__ A, const uint16_t* __restrict__ Bt,
                    uint16_t* __restrict__ Cb, float* __restrict__ Cf,
                    const float* __restrict__ bias, int K, int gx, int chunk) {
  constexpr int MR = BM / 32;                 // m-frags per wave
  __shared__ uint16_t ldsA[2][BM * 32];
  __shared__ uint16_t ldsB[2][128 * 32];
  const int tid = threadIdx.x;
  const int lane = tid & 63;
  const int wid = tid >> 6;
  const int lo = lane & 15, hi = lane >> 4;

  const int id = blockIdx.x;
  const int tilei = (id & 7) * chunk + (id >> 3);
  const int bx = tilei % gx, by = tilei / gx;
  const int row0 = by * BM, col0 = bx * 128;
  const int wr = (wid >> 1) * (BM / 2), wc = (wid & 1) * 64;

  const uint16_t* gA = A + (size_t)(row0 + (tid >> 2)) * K + (tid & 3) * 8;
  const uint16_t* gB = Bt + (size_t)(col0 + (tid >> 2)) * K + (tid & 3) * 8;

  f32x4 acc[MR][4] = {};

  auto stage = [&](int kt, int buf) {
    const uint16_t* a = gA + kt * 32;
    const uint16_t* b = gB + kt * 32;
    char* la = (char*)&ldsA[buf][0] + tid * 16;
    char* lb = (char*)&ldsB[buf][0] + tid * 16;
    GLD16(a, la);
    if constexpr (BM == 128) GLD16(a + (size_t)64 * K, la + 4096);
    GLD16(b, lb);
    GLD16(b + (size_t)64 * K, lb + 4096);
  };

  const int nk = K >> 5;
  stage(0, 0);
  __syncthreads();
  for (int kt = 0; kt < nk; ++kt) {
    const int cur = kt & 1;
    if (kt + 1 < nk) stage(kt + 1, cur ^ 1);
    const uint16_t* lA = &ldsA[cur][0];
    const uint16_t* lB = &ldsB[cur][0];
    bf16x8 af[MR], bfr[4];
#pragma unroll
    for (int m = 0; m < MR; ++m)
      af[m] = *(const bf16x8*)(lA + (wr + m * 16 + lo) * 32 + hi * 8);
#pragma unroll
    for (int n = 0; n < 4; ++n)
      bfr[n] = *(const bf16x8*)(lB + (wc + n * 16 + lo) * 32 + hi * 8);
    __builtin_amdgcn_s_setprio(1);
#pragma unroll
    for (int m = 0; m < MR; ++m)
#pragma unroll
      for (int n = 0; n < 4; ++n)
        acc[m][n] = __builtin_amdgcn_mfma_f32_16x16x32_bf16(af[m], bfr[n], acc[m][n], 0, 0, 0);
    __builtin_amdgcn_s_setprio(0);
    __syncthreads();
  }

#pragma unroll
  for (int m = 0; m < MR; ++m)
#pragma unroll
    for (int n = 0; n < 4; ++n) {
      const int gr0 = row0 + wr + m * 16 + hi * 4;  // 4 consecutive rows (j)
      const int gc = col0 + wc + n * 16 + lo;
      if (EPI == 0) {
        const int which = gc >> 10, c = gc & 1023;
        const int hh = c >> 6, d = c & 63;
        const int bb = gr0 >> 11, s0 = gr0 & 2047;
        if (which == 2) {
          // V^T: [b][h][d][s] -- 4 consecutive s pack into one 8B write
          ushort4 pk;
          pk.x = f2bf(acc[m][n][0]); pk.y = f2bf(acc[m][n][1]);
          pk.z = f2bf(acc[m][n][2]); pk.w = f2bf(acc[m][n][3]);
          *reinterpret_cast<ushort4*>(
              &Cb[2 * HSZ + ((size_t)(bb * H_ + hh) * HD_ + d) * S_ + s0]) = pk;
        } else {
          const float qs = (which == 0) ? SC2F : 1.0f;
#pragma unroll
          for (int j = 0; j < 4; ++j)
            Cb[(size_t)which * HSZ + (((size_t)(bb * H_ + hh) * S_ + s0 + j) * HD_ + d)] =
                f2bf(acc[m][n][j] * qs);
        }
      } else {
#pragma unroll
        for (int j = 0; j < 4; ++j)
          Cf[(size_t)(gr0 + j) * D_ + gc] = acc[m][n][j] + bias[gc];
      }
    }
}

// ---------------- causal flash attention (QBLK=128, exact-packed grid) --------
// Session-best structure (R11: total 108us) -- verbatim.
// 768 blocks = 3 rounds x 256 CU-slots; slot = k*32 + bh -> XCD = bh%8.
// Triplet table: each CU-slot's 3 co-resident jobs sum to EXACTLY 34 iters.
// 4 waves x 32 q rows. Swapped QK^T + transposed PV; softmax per-lane (lo=q).
// K/V XOR-swizzled, double-buffered (50KB LDS -> 3 blocks/CU). Row-sum via
// ones-MFMA. Split jobs (p8..15 kv-halves) write partial (O,m,l).
__global__ __launch_bounds__(256, 3)
void attn_kernel(const uint16_t* __restrict__ QKV, uint16_t* __restrict__ ctx,
                 uint16_t* __restrict__ Opart, float2* __restrict__ ml) {
  __shared__ uint16_t ldsKV[2][2][4096];  // [buf][K/V][ks*2048 + row*32 + col8], swizzled
  __shared__ uint16_t ldsP[128][72];      // P[q][kv], pad 64->72

  // job table: (p<<2)|2|c for split-half c, (p<<2) for unsplit
  static const uint8_t jt[3][8] = {
      {0 << 2, 1 << 2, 2 << 2, 3 << 2, 4 << 2, 5 << 2, 6 << 2, (9 << 2) | 3},
      {(15 << 2) | 2, 7 << 2, (14 << 2) | 2, (14 << 2) | 3,
       (13 << 2) | 3, (12 << 2) | 3, (10 << 2) | 3, (11 << 2) | 2},
      {(15 << 2) | 3, (13 << 2) | 2, (12 << 2) | 2, (10 << 2) | 2,
       (9 << 2) | 2, (8 << 2) | 2, (8 << 2) | 3, (11 << 2) | 3},
  };

  const int tid = threadIdx.x;
  const int lane = tid & 63;
  const int w = tid >> 6;
  const int lo = lane & 15, hi = lane >> 4;
  const int swz = (hi * 8) ^ ((lo & 6) << 2);  // swizzled col for K/V reads

  const int g = blockIdx.x;
  const int bh = g & 31, k = (g >> 5) & 7, r = g >> 8;
  const int j = jt[r][k];
  const int p = j >> 2;
  const bool split = (j & 2) != 0;
  const int c = j & 1;
  const int k0 = (split && c) ? (p + 1) : 0;
  const int k1 = (split && !c) ? (p + 1) : (2 * p + 2);
  const int h = bh & 15, b = bh >> 4;

  const size_t bhs = ((size_t)(b * H_ + h)) * S_ * HD_;
  const uint16_t* Q  = QKV + bhs;                // [s][d], pre-scaled by SC2F
  const uint16_t* Kp = QKV + HSZ + bhs;          // [s][d]
  const uint16_t* Vt = QKV + 2 * HSZ + bhs;      // [d][s]

  // ones A-fragment for the l = sum(P) MFMA
  bf16x8 ones;
#pragma unroll
  for (int e = 0; e < 8; ++e) ones[e] = __builtin_bit_cast(__bf16, (uint16_t)0x3F80);

  // staging with inverse-swizzled global source (rule: swizzle both sides)
  const int srow = tid >> 2;                                  // 0..63
  const int scol = ((tid & 3) ^ ((tid >> 3) & 3)) * 8;        // swizzled col
  auto stage = [&](int kt, int bufi) {
    const uint16_t* gk = Kp + (size_t)(kt * 64 + srow) * HD_ + scol;
    char* lk = (char*)&ldsKV[bufi][0][0] + tid * 16;
    GLD16(gk, lk);             // d 0..31 half
    GLD16(gk + 32, lk + 4096); // d 32..63 half
    const uint16_t* gv = Vt + (size_t)srow * S_ + kt * 64 + scol;
    char* lv = (char*)&ldsKV[bufi][1][0] + tid * 16;
    GLD16(gv, lv);             // kv 0..31 half
    GLD16(gv + 32, lv + 4096); // kv 32..63 half
  };

  const int q0w = p * 128 + w * 32;
  // Q fragments (B-operand of mfma(K,Q)): lane lo = q col, hi*8 = d
  bf16x8 qf[2][2];
#pragma unroll
  for (int mm = 0; mm < 2; ++mm)
#pragma unroll
    for (int ks = 0; ks < 2; ++ks)
      qf[mm][ks] = *(const bf16x8*)(Q + (size_t)(q0w + mm * 16 + lo) * HD_ + ks * 32 + hi * 8);

  f32x4 acco[2][4] = {};       // O^T: lane lo = q, row = d (nd*16+hi*4+j)
  f32x4 lacc[2] = {};          // l accumulator (all 4 rows equal)
  float mstate[2] = {-1e30f, -1e30f};

  stage(k0, k0 & 1);
  asm volatile("s_waitcnt vmcnt(0)" ::: "memory");
  __builtin_amdgcn_s_barrier();
  __builtin_amdgcn_sched_barrier(0);

  for (int kt = k0; kt < k1; ++kt) {
    const int buf = kt & 1;
    if (kt + 1 < k1) stage(kt + 1, buf ^ 1);

    const bool active = (kt * 64) < (q0w + 32);  // wave not fully above diagonal
    if (active) {
      // ---- S^T = K Q^T : lane lo = q, rows kv = n*16+hi*4+j ----
      const uint16_t* lK = &ldsKV[buf][0][0];
      bf16x8 ak[4][2];
#pragma unroll
      for (int n = 0; n < 4; ++n)
#pragma unroll
        for (int ks = 0; ks < 2; ++ks)
          ak[n][ks] = *(const bf16x8*)(lK + ks * 2048 + (n * 16 + lo) * 32 + swz);

      f32x4 st[4][2];
      __builtin_amdgcn_s_setprio(1);
#pragma unroll
      for (int n = 0; n < 4; ++n)
#pragma unroll
        for (int mm = 0; mm < 2; ++mm) {
          f32x4 z = {};
          z = __builtin_amdgcn_mfma_f32_16x16x32_bf16(ak[n][0], qf[mm][0], z, 0, 0, 0);
          st[n][mm] = __builtin_amdgcn_mfma_f32_16x16x32_bf16(ak[n][1], qf[mm][1], z, 0, 0, 0);
        }
      __builtin_amdgcn_s_setprio(0);

      // ---- causal mask (tiles overlapping this wave's rows) ----
      if (kt * 64 + 63 > q0w) {
#pragma unroll
        for (int n = 0; n < 4; ++n)
#pragma unroll
          for (int mm = 0; mm < 2; ++mm) {
            const int qg = q0w + mm * 16 + lo;
#pragma unroll
            for (int jj = 0; jj < 4; ++jj) {
              int kvg = kt * 64 + n * 16 + hi * 4 + jj;
              if (kvg > qg) st[n][mm][jj] = -1e30f;
            }
          }
      }

      // ---- online softmax, per-lane state (q = lo) ----
#pragma unroll
      for (int mm = 0; mm < 2; ++mm) {
        float t0 = fmax3(st[0][mm][0], st[0][mm][1], st[0][mm][2]);
        float t1 = fmax3(t0, st[0][mm][3], st[1][mm][0]);
        float t2 = fmax3(t1, st[1][mm][1], st[1][mm][2]);
        float t3 = fmax3(t2, st[1][mm][3], st[2][mm][0]);
        float t4 = fmax3(t3, st[2][mm][1], st[2][mm][2]);
        float t5 = fmax3(t4, st[2][mm][3], st[3][mm][0]);
        float t6 = fmax3(t5, st[3][mm][1], st[3][mm][2]);
        float vmax = fmaxf(t6, st[3][mm][3]);
        vmax = fmaxf(vmax, __shfl_xor(vmax, 16));
        vmax = fmaxf(vmax, __shfl_xor(vmax, 32));

        if (__any(vmax > mstate[mm] + 8.f)) {  // defer-max rescale
          float mnew = fmaxf(mstate[mm], vmax);
          float sc = EXP2(mstate[mm] - mnew);
          mstate[mm] = mnew;
          lacc[mm] *= sc;
#pragma unroll
          for (int nd = 0; nd < 4; ++nd)
#pragma unroll
            for (int jj = 0; jj < 4; ++jj) acco[mm][nd][jj] *= sc;
        }

#pragma unroll
        for (int n = 0; n < 4; ++n) {
          ushort4 pk;
          pk.x = f2bf(EXP2(st[n][mm][0] - mstate[mm]));
          pk.y = f2bf(EXP2(st[n][mm][1] - mstate[mm]));
          pk.z = f2bf(EXP2(st[n][mm][2] - mstate[mm]));
          pk.w = f2bf(EXP2(st[n][mm][3] - mstate[mm]));
          *reinterpret_cast<ushort4*>(&ldsP[w * 32 + mm * 16 + lo][n * 16 + hi * 4]) = pk;
        }
      }

      // ---- O^T += V^T P^T ; l += ones * P^T ----
      const uint16_t* lV = &ldsKV[buf][1][0];
      bf16x8 ap[2][2], bv[4][2];
#pragma unroll
      for (int mm = 0; mm < 2; ++mm)
#pragma unroll
        for (int ks = 0; ks < 2; ++ks)
          ap[mm][ks] = *(const bf16x8*)(&ldsP[w * 32 + mm * 16 + lo][ks * 32 + hi * 8]);
#pragma unroll
      for (int nd = 0; nd < 4; ++nd)
#pragma unroll
        for (int ks = 0; ks < 2; ++ks)
          bv[nd][ks] = *(const bf16x8*)(lV + ks * 2048 + (nd * 16 + lo) * 32 + swz);
      __builtin_amdgcn_s_setprio(1);
#pragma unroll
      for (int mm = 0; mm < 2; ++mm) {
        lacc[mm] = __builtin_amdgcn_mfma_f32_16x16x32_bf16(ones, ap[mm][0], lacc[mm], 0, 0, 0);
        lacc[mm] = __builtin_amdgcn_mfma_f32_16x16x32_bf16(ones, ap[mm][1], lacc[mm], 0, 0, 0);
#pragma unroll
        for (int nd = 0; nd < 4; ++nd) {
          acco[mm][nd] = __builtin_amdgcn_mfma_f32_16x16x32_bf16(bv[nd][0], ap[mm][0], acco[mm][nd], 0, 0, 0);
          acco[mm][nd] = __builtin_amdgcn_mfma_f32_16x16x32_bf16(bv[nd][1], ap[mm][1], acco[mm][nd], 0, 0, 0);
        }
      }
      __builtin_amdgcn_s_setprio(0);
    }

    asm volatile("s_waitcnt vmcnt(0)" ::: "memory");
    __builtin_amdgcn_s_barrier();
    __builtin_amdgcn_sched_barrier(0);
  }

  if (!split) {
    // ---- normalize (per-lane) + packed ctx write ----
#pragma unroll
    for (int mm = 0; mm < 2; ++mm) {
      const float inv = 1.f / lacc[mm][0];
      uint16_t* crow = ctx + (size_t)(b * S_ + q0w + mm * 16 + lo) * D_ + h * HD_;
#pragma unroll
      for (int nd = 0; nd < 4; ++nd) {
        ushort4 pk;
        pk.x = f2bf(acco[mm][nd][0] * inv); pk.y = f2bf(acco[mm][nd][1] * inv);
        pk.z = f2bf(acco[mm][nd][2] * inv); pk.w = f2bf(acco[mm][nd][3] * inv);
        *reinterpret_cast<ushort4*>(crow + nd * 16 + hi * 4) = pk;
      }
    }
  } else {
    // ---- write partial O (unnormalized bf16) + (m,l): idx over (bh,p,c) ----
    const int idx = ((bh * 8) + (p - 8)) * 2 + c;
    uint16_t* op = Opart + (size_t)idx * 8192;   // 128 q x 64 d
#pragma unroll
    for (int mm = 0; mm < 2; ++mm) {
      const int qloc = w * 32 + mm * 16 + lo;
#pragma unroll
      for (int nd = 0; nd < 4; ++nd) {
        ushort4 pk;
        pk.x = f2bf(acco[mm][nd][0]); pk.y = f2bf(acco[mm][nd][1]);
        pk.z = f2bf(acco[mm][nd][2]); pk.w = f2bf(acco[mm][nd][3]);
        *reinterpret_cast<ushort4*>(op + qloc * 64 + nd * 16 + hi * 4) = pk;
      }
      if (hi == 0) ml[idx * 128 + qloc] = make_float2(mstate[mm], lacc[mm][0]);
    }
  }
}

// ---------------- merge kv-split partials -> ctx ------------------------------
// 512 blocks x 256 threads; thread -> (row = (bh,si,q), 16-d chunk).
__global__ void merge_kernel(const uint16_t* __restrict__ Opart,
                             const float2* __restrict__ ml,
                             uint16_t* __restrict__ ctx) {
  const int t = blockIdx.x * 256 + threadIdx.x;   // 131072 threads
  const int dh = t & 3, row = t >> 2;
  const int q = row & 127, si = (row >> 7) & 7, bh = row >> 10;
  const int h = bh & 15, b = bh >> 4;
  const int p = 8 + si;
  const int base = (bh * 8 + si) * 2;

  const float2 A = ml[base * 128 + q];
  const float2 Bv = ml[base * 128 + 128 + q];
  const float m = fmaxf(A.x, Bv.x);
  float sa = EXP2(A.x - m), sb = EXP2(Bv.x - m);
  const float inv = 1.f / (A.y * sa + Bv.y * sb);
  sa *= inv; sb *= inv;

  const uint16_t* Oa = Opart + (size_t)base * 8192 + q * 64 + dh * 16;
  const uint16_t* Ob = Oa + 8192;
  uint16_t* pc = ctx + ((size_t)(b * S_) + p * 128 + q) * D_ + h * HD_ + dh * 16;
#pragma unroll
  for (int hf = 0; hf < 2; ++hf) {
    int4 va = ((const int4*)Oa)[hf], vb = ((const int4*)Ob)[hf];
    const uint16_t* ua = (const uint16_t*)&va;
    const uint16_t* ub = (const uint16_t*)&vb;
    int4 vo;
    uint16_t* uo = (uint16_t*)&vo;
#pragma unroll
    for (int i = 0; i < 8; ++i)
      uo[i] = f2bf(bf2f(ua[i]) * sa + bf2f(ub[i]) * sb);
    ((int4*)pc)[hf] = vo;
  }
}

extern "C" void kernel_launch(void* const* d_in, const int* in_sizes, int n_in,
                              void* d_out, int out_size, void* d_ws, size_t ws_size,
                              hipStream_t stream) {
  (void)in_sizes; (void)n_in; (void)out_size; (void)ws_size;
  const float* x  = (const float*)d_in[0];
  const float* Wq = (const float*)d_in[1];
  const float* Wk = (const float*)d_in[2];
  const float* Wv = (const float*)d_in[3];
  const float* Wo = (const float*)d_in[4];
  const float* bo = (const float*)d_in[5];
  float* out = (float*)d_out;

  uint16_t* ws  = (uint16_t*)d_ws;
  uint16_t* xb  = ws;                         // 4096*1024 (dead after gemm0)
  uint16_t* Wt  = xb + (size_t)M_ * D_;       // 4*1024*1024 (Wq^T dead after gemm0)
  uint16_t* QKV = Wt + (size_t)4 * D_ * D_;   // 3*HSZ (Q, K, V^T)
  uint16_t* ctx = QKV + 3 * HSZ;              // 4096*1024   (~48 MB total)
  // kv-split partials reuse dead regions (attn runs after gemm0):
  uint16_t* Opart = xb;                       // 32*8*2*8192 elems = 8 MB (== xb)
  float2*   mlbuf = (float2*)Wt;              // 32*16*128 float2 = 512 KB (in dead Wq^T)

  prep_kernel<<<8192, 256, 0, stream>>>(x, Wq, Wk, Wv, Wo, xb, Wt);
  // gemm<0>: 24x32 tiles = 768 blocks, 3/CU uniform (chunk=96)
  gemm_bt_kernel<0, 128, 3><<<768, 256, 0, stream>>>(xb, Wt, QKV, nullptr, nullptr, D_, 24, 96);
  attn_kernel<<<768, 256, 0, stream>>>(QKV, ctx, Opart, mlbuf);
  merge_kernel<<<512, 256, 0, stream>>>(Opart, mlbuf, ctx);
  // gemm<1>: BM=64 -> 64x8 tiles = 512 blocks, 2/CU (chunk=64)
  gemm_bt_kernel<1, 64, 2><<<512, 256, 0, stream>>>(ctx, Wt + (size_t)3 * D_ * D_, nullptr, out, bo, D_, 8, 64);
}